// Round 6
// baseline (411.669 us; speedup 1.0000x reference)
//
#include <hip/hip_runtime.h>

#define BB 8
#define TT 2048
#define DD 768
#define EE 2304
#define MM (BB * TT)
#define MHK_ 768
#define LOG2E 1.44269504088896340736f

typedef __attribute__((ext_vector_type(8))) _Float16 f16x8;
typedef __attribute__((ext_vector_type(4))) float f32x4;

typedef const __attribute__((address_space(1))) void* gp_t;
typedef __attribute__((address_space(3))) void* lp_t;

__device__ __forceinline__ float fast_exp2(float x) { return __builtin_amdgcn_exp2f(x); }

// ---------- fused prep: zero l + x->f16 cast + tiled coalesced w transposes ----------
__global__ __launch_bounds__(256)
void k_prep(const float* __restrict__ x, const float* __restrict__ w_qkv,
            const float* __restrict__ w_out, _Float16* __restrict__ xh,
            _Float16* __restrict__ w_qkvT, _Float16* __restrict__ w_outT,
            float* __restrict__ lbuf) {
  __shared__ float tile[32][33];
  int bid = blockIdx.x;
  if (bid < 16) {
    lbuf[bid * 1024 + threadIdx.x * 4 + 0] = 0.f;
    lbuf[bid * 1024 + threadIdx.x * 4 + 1] = 0.f;
    lbuf[bid * 1024 + threadIdx.x * 4 + 2] = 0.f;
    lbuf[bid * 1024 + threadIdx.x * 4 + 3] = 0.f;
    return;
  }
  if (bid < 16 + 6144) {
    int idx = (bid - 16) * 256 + threadIdx.x;  // 8 f32 -> 8 f16 per thread
    const float4* p = (const float4*)(x + idx * 8);
    float4 a = p[0], b = p[1];
    f16x8 o;
    o[0] = (_Float16)a.x; o[1] = (_Float16)a.y; o[2] = (_Float16)a.z; o[3] = (_Float16)a.w;
    o[4] = (_Float16)b.x; o[5] = (_Float16)b.y; o[6] = (_Float16)b.z; o[7] = (_Float16)b.w;
    *(f16x8*)(xh + idx * 8) = o;
    return;
  }
  const float* in;
  _Float16* out;
  int R, C, t;
  if (bid < 6160 + 1728) {
    t = bid - 6160; in = w_qkv; out = w_qkvT; R = DD; C = EE;   // 24 x 72 tiles
  } else {
    t = bid - 7888; in = w_out; out = w_outT; R = DD; C = DD;   // 24 x 24 tiles
  }
  const int tpr = C / 32;
  const int r0 = (t / tpr) * 32, c0 = (t - (t / tpr) * tpr) * 32;
  const int tx = threadIdx.x & 31, ty = threadIdx.x >> 5;
  for (int k = 0; k < 4; k++)
    tile[ty + k * 8][tx] = in[(size_t)(r0 + ty + k * 8) * C + c0 + tx];
  __syncthreads();
  for (int k = 0; k < 4; k++)
    out[(size_t)(c0 + ty + k * 8) * R + r0 + tx] = (_Float16)tile[tx][ty + k * 8];
}

// ---------- MFMA GEMM: C[M,N] = A[M,K] * Bt[N,K]^T ----------
// 128 x (NJ*32) tile, BK=32, double-buffered glds staging, XOR bank swizzle.
// NJ=4: 128x128 tile (32KB LDS); NJ=2: 128x64 tile (24KB LDS, 32 AGPR acc ->
// ~2x resident waves for the grid-starved K=2048 kernels).
// XCD decode: !XN partitions M across XCDs (gx = n-blocks, gyp = m-blocks/XCD);
// XN partitions N (gx = m-blocks, gyp = n-blocks/XCD).
// Epilogues: QKV (bias then Q log2-scale), S (P=exp2(s-24)+atomic row sums),
// FINAL (acc/l + bias, f32), plain f16.
template<int NJ, bool OUT_F16, bool HAS_BIAS, bool QSCALE, bool EXP_LSUM, bool ROWSCALE, bool XN>
__global__ __launch_bounds__(256)
void k_gemm(const _Float16* __restrict__ A, const _Float16* __restrict__ Bt,
            const float* __restrict__ bias, void* __restrict__ Cv,
            float* __restrict__ lbuf,
            int lda, int ldb, int ldc, int Kd,
            long long strideA, long long strideB, long long strideC,
            int gx, int gyp, float qscale) {
  const int TN = NJ * 32;
  __shared__ __align__(16) _Float16 As[2][128 * 32];
  __shared__ __align__(16) _Float16 Bs[2][NJ * 32 * 32];
  const int tid = threadIdx.x;
  const int lane = tid & 63;
  const int w = tid >> 6;
  const int quad = lane >> 4;
  const int l16 = lane & 15;

  // XCD-aware decode
  const int bid = blockIdx.x;
  const int xcd = bid & 7;
  int local = bid >> 3;
  const int perz = gx * gyp;
  const int z = local / perz;
  local -= z * perz;
  const int i1 = local / gx;
  const int i0 = local - i1 * gx;
  const int m0 = XN ? i0 * 128 : (xcd * gyp + i1) * 128;
  const int n0 = XN ? (xcd * gyp + i1) * TN : i0 * TN;

  const int wr = (w >> 1) * 64;
  const int wc = (w & 1) * (TN / 2);

  // staging: row = tid>>2, fetched chunk (tid&3)^(row&3)  (XOR swizzle)
  const int srow = tid >> 2;
  const int scc = ((tid & 3) ^ ((tid >> 2) & 3)) * 8;
  const _Float16* Abase = A + (long long)z * strideA + (size_t)(m0 + srow) * lda + scc;
  const _Float16* Bbase = Bt + (long long)z * strideB + (size_t)(n0 + srow) * ldb + scc;
  const size_t a64 = (size_t)64 * lda;
  const size_t b64 = (size_t)64 * ldb;
  const int wbase = (w * 16) * 32;  // wave-uniform LDS dest

  f32x4 acc[4][NJ];
  for (int i = 0; i < 4; i++)
    for (int j = 0; j < NJ; j++)
      for (int r = 0; r < 4; r++) acc[i][j][r] = 0.f;

  const int fsw = (quad ^ (l16 & 3)) * 8;  // fragment k-chunk slot

  // prologue: tile 0 into buffer 0
  __builtin_amdgcn_global_load_lds((gp_t)(Abase), (lp_t)(&As[0][wbase]), 16, 0, 0);
  __builtin_amdgcn_global_load_lds((gp_t)(Abase + a64), (lp_t)(&As[0][wbase + 64 * 32]), 16, 0, 0);
  __builtin_amdgcn_global_load_lds((gp_t)(Bbase), (lp_t)(&Bs[0][wbase]), 16, 0, 0);
  if (NJ == 4)
    __builtin_amdgcn_global_load_lds((gp_t)(Bbase + b64), (lp_t)(&Bs[0][wbase + 64 * 32]), 16, 0, 0);

  const int niter = Kd >> 5;
  for (int it = 0; it < niter; it++) {
    const int p = it & 1;
    __syncthreads();  // drains tile-it loads (issued one iter ago / prologue)
    if (it + 1 < niter) {
      const int pn = p ^ 1;
      const size_t ko = (size_t)(it + 1) * 32;
      __builtin_amdgcn_global_load_lds((gp_t)(Abase + ko), (lp_t)(&As[pn][wbase]), 16, 0, 0);
      __builtin_amdgcn_global_load_lds((gp_t)(Abase + ko + a64), (lp_t)(&As[pn][wbase + 64 * 32]), 16, 0, 0);
      __builtin_amdgcn_global_load_lds((gp_t)(Bbase + ko), (lp_t)(&Bs[pn][wbase]), 16, 0, 0);
      if (NJ == 4)
        __builtin_amdgcn_global_load_lds((gp_t)(Bbase + ko + b64), (lp_t)(&Bs[pn][wbase + 64 * 32]), 16, 0, 0);
    }
    f16x8 af[4], bf[NJ];
    for (int i = 0; i < 4; i++) af[i] = *(const f16x8*)&As[p][(wr + i * 16 + l16) * 32 + fsw];
    for (int j = 0; j < NJ; j++) bf[j] = *(const f16x8*)&Bs[p][(wc + j * 16 + l16) * 32 + fsw];
    for (int i = 0; i < 4; i++)
      for (int j = 0; j < NJ; j++)
        acc[i][j] = __builtin_amdgcn_mfma_f32_16x16x32_f16(af[i], bf[j], acc[i][j], 0, 0, 0);
  }

  const long long cbase = (long long)z * strideC;

  if (EXP_LSUM) {
    float psum[4][4];
    for (int i = 0; i < 4; i++)
      for (int r = 0; r < 4; r++) psum[i][r] = 0.f;
    for (int j = 0; j < NJ; j++) {
      int col = n0 + wc + j * 16 + l16;
      for (int i = 0; i < 4; i++) {
        int row = m0 + wr + i * 16 + quad * 4;
        for (int r = 0; r < 4; r++) {
          float p = fast_exp2(acc[i][j][r] - 24.f);
          psum[i][r] += p;
          ((_Float16*)Cv)[cbase + (size_t)(row + r) * ldc + col] = (_Float16)p;
        }
      }
    }
    for (int i = 0; i < 4; i++)
      for (int r = 0; r < 4; r++) {
        float v = psum[i][r];
        v += __shfl_xor(v, 1, 64);
        v += __shfl_xor(v, 2, 64);
        v += __shfl_xor(v, 4, 64);
        v += __shfl_xor(v, 8, 64);
        if (l16 == 0)
          atomicAdd(&lbuf[z * TT + m0 + wr + i * 16 + quad * 4 + r], v);
      }
    return;
  }

  float invr[4][4];
  if (ROWSCALE) {
    for (int i = 0; i < 4; i++)
      for (int r = 0; r < 4; r++)
        invr[i][r] = 1.f / lbuf[z * TT + m0 + wr + i * 16 + quad * 4 + r];
  }

  for (int j = 0; j < NJ; j++) {
    int col = n0 + wc + j * 16 + l16;
    float bv = HAS_BIAS ? bias[col] : 0.f;
    for (int i = 0; i < 4; i++) {
      int row = m0 + wr + i * 16 + quad * 4;
      for (int r = 0; r < 4; r++) {
        float v = acc[i][j][r];
        if (QSCALE) {                       // QKV: bias, then Q log2-scale
          v += bv;
          if (col < MHK_) v *= qscale;
        } else if (ROWSCALE) {              // FINAL: acc/l + bias
          v = v * invr[i][r] + bv;
        } else {
          v += bv;
        }
        if (OUT_F16)
          ((_Float16*)Cv)[cbase + (size_t)(row + r) * ldc + col] = (_Float16)v;
        else
          ((float*)Cv)[cbase + (size_t)(row + r) * ldc + col] = v;
      }
    }
  }
}

extern "C" void kernel_launch(void* const* d_in, const int* in_sizes, int n_in,
                              void* d_out, int out_size, void* d_ws, size_t ws_size,
                              hipStream_t stream) {
  const float* x = (const float*)d_in[0];
  const float* w_qkv = (const float*)d_in[1];
  const float* b_qkv = (const float*)d_in[2];
  const float* w_out = (const float*)d_in[3];
  const float* b_out = (const float*)d_in[4];

  _Float16* ws = (_Float16*)d_ws;
  _Float16* w_qkvT = ws;                          // [2304][768]
  _Float16* w_outT = w_qkvT + (size_t)EE * DD;    // [768][768]
  _Float16* qkv = w_outT + (size_t)DD * DD;       // [16384][2304] (Q pre-scaled)
  _Float16* VWt = qkv + (size_t)MM * EE;          // [8][768 d'][2048 t] = (V·W)^T
  _Float16* P = VWt + (size_t)BB * DD * TT;       // [8][2048][2048] = exp2(S-24)
  float* lbuf = (float*)(P + (size_t)BB * TT * TT); // [16384] row sums
  _Float16* xh = (_Float16*)(lbuf + MM);          // [16384][768] x in f16

  // 0. fused prep (l zero + x cast + tiled weight transposes)
  k_prep<<<8464, 256, 0, stream>>>(x, w_qkv, w_out, xh, w_qkvT, w_outT, lbuf);
  // 1. qkv projection (+bias, Q scaled into log2 domain)
  k_gemm<4, true, true, true, false, false, false><<<2304, 256, 0, stream>>>(
      xh, w_qkvT, b_qkv, qkv, nullptr, DD, DD, EE, DD, 0, 0, 0, 18, 16, 0.125f * LOG2E);
  // 2. VWt = (w_out^T)·(V^T)  [batched over z via B; A shared]
  k_gemm<2, true, false, false, false, false, true><<<1536, 256, 0, stream>>>(
      w_outT, qkv + 2 * MHK_, nullptr, VWt, nullptr, DD, EE, TT, DD,
      0, (long long)TT * EE, (long long)DD * TT, 6, 4, 1.f);
  // 3. P = exp2(Q K^T - 24) + atomic row sums (batched)
  k_gemm<4, true, false, false, true, false, false><<<2048, 256, 0, stream>>>(
      qkv, qkv + MHK_, nullptr, P, lbuf, EE, EE, TT, DD,
      (long long)TT * EE, (long long)TT * EE, (long long)TT * TT, 16, 2, 1.f);
  // 4. out = P·VWt / l + b_out  (fp32, batched)
  k_gemm<2, false, true, false, false, true, false><<<1536, 256, 0, stream>>>(
      P, VWt, b_out, d_out, lbuf, TT, TT, DD, TT,
      (long long)TT * TT, (long long)DD * TT, (long long)TT * DD, 12, 2, 1.f);
}